// Round 19
// baseline (525.198 us; speedup 1.0000x reference)
//
#include <hip/hip_runtime.h>
#include <math.h>

#define BB 2
#define CDIM 256
#define NQ 4096   // 16*16*16
#define NK 2048   // 8*16*16
#define BH 16
#define TOPK 1024
#define NPQ (BH*NQ)   // 65536
#define NPK (BH*NK)   // 32768

typedef __attribute__((ext_vector_type(8))) short bfx8;
typedef __attribute__((ext_vector_type(8))) _Float16 hfx8;
typedef __attribute__((ext_vector_type(2))) __fp16 fpx2;
typedef __attribute__((ext_vector_type(4))) float fx4;
typedef __attribute__((ext_vector_type(4))) unsigned short us4;

__device__ inline unsigned short f2bf(float x) {
  unsigned u = __float_as_uint(x);
  return (unsigned short)((u + 0x7fffu + ((u >> 16) & 1u)) >> 16);
}
__device__ inline unsigned short f2h_bits(float x) {
  _Float16 h = (_Float16)x;
  unsigned short u;
  __builtin_memcpy(&u, &h, 2);
  return u;
}
__device__ inline float h_bits2f(unsigned short u) {
  _Float16 h;
  __builtin_memcpy(&h, &u, 2);
  return (float)h;
}

// ------- channel LayerNorm -> transposed split-f16 [b][n][C] (hi, lo*2048) ---
__global__ __launch_bounds__(256) void chan_ln_tsplit_k(
    const float* __restrict__ x, const float* __restrict__ g,
    const float* __restrict__ bta, unsigned short* __restrict__ yh,
    unsigned short* __restrict__ yl, int C, int N) {
  __shared__ float tile[4][64][65];
  __shared__ float p1[4][64], p2[4][64];
  __shared__ float mArr[64], invArr[64];
  int t = threadIdx.x, lane = t & 63, wv = t >> 6;
  int n0 = blockIdx.x * 64, bi = blockIdx.y;
  const float* xb = x + (size_t)bi * C * N + n0 + lane;
  float s = 0.f, s2 = 0.f;
  for (int cl = 0; cl < 64; ++cl) {
    float v = xb[(size_t)(wv * 64 + cl) * N];
    tile[wv][cl][lane] = v;
    s += v;
    s2 += v * v;
  }
  p1[wv][lane] = s;
  p2[wv][lane] = s2;
  __syncthreads();
  if (t < 64) {
    float ts = p1[0][t] + p1[1][t] + p1[2][t] + p1[3][t];
    float ts2 = p2[0][t] + p2[1][t] + p2[2][t] + p2[3][t];
    float m = ts / C;
    float var = ts2 / C - m * m;
    mArr[t] = m;
    invArr[t] = 1.f / (sqrtf(fmaxf(var, 0.f)) + 1e-6f);
  }
  __syncthreads();
  int c = wv * 64 + lane;  // lane = channel in phase 2
  float gc = g[c], bc = bta[c];
  unsigned short* ohb = yh + ((size_t)bi * N + n0) * C + c;
  unsigned short* olb = yl + ((size_t)bi * N + n0) * C + c;
  for (int pl = 0; pl < 64; ++pl) {
    float v = tile[wv][lane][pl];
    float ln = gc * (v - mArr[pl]) * invArr[pl] + bc;
    unsigned short hb = f2h_bits(ln);
    ohb[(size_t)pl * C] = hb;
    olb[(size_t)pl * C] = f2h_bits((ln - h_bits2f(hb)) * 2048.f);
  }
}

// ------- MFMA GEMM (w_out), LDS-staged X pipeline: Y[b][o][n] ----------------
__global__ __launch_bounds__(256) void gemm_mfma_k(
    const float* __restrict__ W, const unsigned short* __restrict__ Xh,
    const unsigned short* __restrict__ Xl, float* __restrict__ Y,
    int O, int C, int N) {
  __shared__ __align__(16) unsigned short xlds[2][64][64];  // [buf][row][hi32|lo32]
  int t = threadIdx.x, lane = t & 63, wv = t >> 6;
  int lq = lane & 15, lg = lane >> 4;
  int n0 = blockIdx.x * 64, o0 = blockIdx.y * 64 + wv * 16;
  int b = blockIdx.z;
  const unsigned short* xbh = Xh + ((size_t)b * N + n0) * C;
  const unsigned short* xbl = Xl + ((size_t)b * N + n0) * C;
  const float* wr = W + (size_t)(o0 + lq) * C;

  int a = t * 16;
  int srow = a >> 6;
  int schunk = (a >> 4) & 3;
  const unsigned short* gsh = xbh + (size_t)srow * C + schunk * 8;
  const unsigned short* gsl = xbl + (size_t)srow * C + schunk * 8;
  int swz = (srow & 7) << 4;
  int wbh = srow * 128 + ((schunk * 16) ^ swz);
  int wbl = srow * 128 + ((64 + schunk * 16) ^ swz);
  int rswz = (lq & 7) << 4;
  int xh0 = (lg * 16) ^ rswz;
  int xl0 = (64 + lg * 16) ^ rswz;

  fx4 ahi[4], alo[4];
  for (int nt = 0; nt < 4; ++nt) {
    ahi[nt] = (fx4){0.f, 0.f, 0.f, 0.f};
    alo[nt] = (fx4){0.f, 0.f, 0.f, 0.f};
  }

  {
    uint4 h0 = *(const uint4*)(gsh);
    uint4 l0 = *(const uint4*)(gsl);
    *(uint4*)((char*)&xlds[0][0][0] + wbh) = h0;
    *(uint4*)((char*)&xlds[0][0][0] + wbl) = l0;
  }
  float4 w0c = *(const float4*)(wr + lg * 8);
  float4 w1c = *(const float4*)(wr + lg * 8 + 4);

  int nsteps = C / 32;
  for (int s = 0; s < nsteps; ++s) {
    int cur = s & 1;
    __syncthreads();
    uint4 nh, nl;
    float4 nw0, nw1;
    if (s < nsteps - 1) {
      nh = *(const uint4*)(gsh + (s + 1) * 32);
      nl = *(const uint4*)(gsl + (s + 1) * 32);
      nw0 = *(const float4*)(wr + (s + 1) * 32 + lg * 8);
      nw1 = *(const float4*)(wr + (s + 1) * 32 + lg * 8 + 4);
    }
    __builtin_amdgcn_sched_barrier(0);
    float wv8[8] = {w0c.x, w0c.y, w0c.z, w0c.w, w1c.x, w1c.y, w1c.z, w1c.w};
    hfx8 ah, al;
#pragma unroll
    for (int i = 0; i < 8; ++i) {
      _Float16 hh = (_Float16)wv8[i];
      ah[i] = hh;
      al[i] = (_Float16)((wv8[i] - (float)hh) * 2048.f);
    }
    const char* Xb = (const char*)&xlds[cur][0][0];
#pragma unroll
    for (int nt = 0; nt < 4; ++nt) {
      int rb = (nt * 16 + lq) * 128;
      hfx8 bh = *(const hfx8*)(Xb + rb + xh0);
      hfx8 bl = *(const hfx8*)(Xb + rb + xl0);
      ahi[nt] = __builtin_amdgcn_mfma_f32_16x16x32_f16(ah, bh, ahi[nt], 0, 0, 0);
      alo[nt] = __builtin_amdgcn_mfma_f32_16x16x32_f16(al, bh, alo[nt], 0, 0, 0);
      alo[nt] = __builtin_amdgcn_mfma_f32_16x16x32_f16(ah, bl, alo[nt], 0, 0, 0);
    }
    __builtin_amdgcn_sched_barrier(0);
    if (s < nsteps - 1) {
      *(uint4*)((char*)&xlds[cur ^ 1][0][0] + wbh) = nh;
      *(uint4*)((char*)&xlds[cur ^ 1][0][0] + wbl) = nl;
      w0c = nw0;
      w1c = nw1;
    }
  }
  float* yb = Y + ((size_t)b * O + o0) * N + n0;
#pragma unroll
  for (int nt = 0; nt < 4; ++nt)
#pragma unroll
    for (int r = 0; r < 4; ++r)
      yb[(size_t)(lg * 4 + r) * N + nt * 16 + lq] = ahi[nt][r] + alo[nt][r] * (1.f / 2048.f);
}

// ------- fused GEMM + head-fold + L2-norm + multi-format emit ---------------
template <int PATH>
__global__ __launch_bounds__(256) void gemmfold_k(
    const float* __restrict__ W, const unsigned short* __restrict__ Xh,
    const unsigned short* __restrict__ Xl, float* __restrict__ fq,
    unsigned short* __restrict__ sh, unsigned short* __restrict__ sl,
    unsigned short* __restrict__ b16, float* __restrict__ fv,
    int C, int N) {
  __shared__ __align__(16) unsigned short xlds[2][64][64];  // [buf][row][hi32|lo32]
  __shared__ float ftile[64][65];
  __shared__ float part[4][64];
  __shared__ float invArr[64];
  int t = threadIdx.x, lane = t & 63, wv = t >> 6;
  int lq = lane & 15, lg = lane >> 4;
  int n0 = blockIdx.x * 64, o0 = blockIdx.y * 64 + wv * 16;
  int b = blockIdx.z;
  bool isV = (PATH == 1) && (blockIdx.y >= 8);
  int h = (PATH == 1) ? (blockIdx.y & 7) : blockIdx.y;
  const unsigned short* xbh = Xh + ((size_t)b * N + n0) * C;
  const unsigned short* xbl = Xl + ((size_t)b * N + n0) * C;
  const float* wr = W + (size_t)(o0 + lq) * C;

  int a = t * 16;
  int srow = a >> 6;
  int schunk = (a >> 4) & 3;
  const unsigned short* gsh = xbh + (size_t)srow * C + schunk * 8;
  const unsigned short* gsl = xbl + (size_t)srow * C + schunk * 8;
  int swz = (srow & 7) << 4;
  int wbh = srow * 128 + ((schunk * 16) ^ swz);
  int wbl = srow * 128 + ((64 + schunk * 16) ^ swz);
  int rswz = (lq & 7) << 4;
  int xh0 = (lg * 16) ^ rswz;
  int xl0 = (64 + lg * 16) ^ rswz;

  fx4 ahi[4], alo[4];
  for (int nt = 0; nt < 4; ++nt) {
    ahi[nt] = (fx4){0.f, 0.f, 0.f, 0.f};
    alo[nt] = (fx4){0.f, 0.f, 0.f, 0.f};
  }

  {
    uint4 h0 = *(const uint4*)(gsh);
    uint4 l0 = *(const uint4*)(gsl);
    *(uint4*)((char*)&xlds[0][0][0] + wbh) = h0;
    *(uint4*)((char*)&xlds[0][0][0] + wbl) = l0;
  }
  float4 w0c = *(const float4*)(wr + lg * 8);
  float4 w1c = *(const float4*)(wr + lg * 8 + 4);

  for (int s = 0; s < 8; ++s) {
    int cur = s & 1;
    __syncthreads();
    uint4 nh, nl;
    float4 nw0, nw1;
    if (s < 7) {
      nh = *(const uint4*)(gsh + (s + 1) * 32);
      nl = *(const uint4*)(gsl + (s + 1) * 32);
      nw0 = *(const float4*)(wr + (s + 1) * 32 + lg * 8);
      nw1 = *(const float4*)(wr + (s + 1) * 32 + lg * 8 + 4);
    }
    __builtin_amdgcn_sched_barrier(0);
    float wv8[8] = {w0c.x, w0c.y, w0c.z, w0c.w, w1c.x, w1c.y, w1c.z, w1c.w};
    hfx8 ah, al;
#pragma unroll
    for (int i = 0; i < 8; ++i) {
      _Float16 hh = (_Float16)wv8[i];
      ah[i] = hh;
      al[i] = (_Float16)((wv8[i] - (float)hh) * 2048.f);
    }
    const char* Xb = (const char*)&xlds[cur][0][0];
#pragma unroll
    for (int nt = 0; nt < 4; ++nt) {
      int rb = (nt * 16 + lq) * 128;
      hfx8 bh = *(const hfx8*)(Xb + rb + xh0);
      hfx8 bl = *(const hfx8*)(Xb + rb + xl0);
      ahi[nt] = __builtin_amdgcn_mfma_f32_16x16x32_f16(ah, bh, ahi[nt], 0, 0, 0);
      alo[nt] = __builtin_amdgcn_mfma_f32_16x16x32_f16(al, bh, alo[nt], 0, 0, 0);
      alo[nt] = __builtin_amdgcn_mfma_f32_16x16x32_f16(ah, bl, alo[nt], 0, 0, 0);
    }
    __builtin_amdgcn_sched_barrier(0);
    if (s < 7) {
      *(uint4*)((char*)&xlds[cur ^ 1][0][0] + wbh) = nh;
      *(uint4*)((char*)&xlds[cur ^ 1][0][0] + wbl) = nl;
      w0c = nw0;
      w1c = nw1;
    }
  }

  float val[4][4];
#pragma unroll
  for (int nt = 0; nt < 4; ++nt)
#pragma unroll
    for (int r = 0; r < 4; ++r)
      val[nt][r] = ahi[nt][r] + alo[nt][r] * (1.f / 2048.f);
  __syncthreads();
  if (!isV) {
#pragma unroll
    for (int nt = 0; nt < 4; ++nt) {
      float ss = val[nt][0] * val[nt][0] + val[nt][1] * val[nt][1] +
                 val[nt][2] * val[nt][2] + val[nt][3] * val[nt][3];
      ss += __shfl_xor(ss, 16);
      ss += __shfl_xor(ss, 32);
      if (lg == 0) part[wv][nt * 16 + lq] = ss;
    }
    __syncthreads();
    if (t < 64) {
      float tot = part[0][t] + part[1][t] + part[2][t] + part[3][t];
      invArr[t] = 1.f / fmaxf(sqrtf(tot), 1e-12f);
    }
    __syncthreads();
#pragma unroll
    for (int nt = 0; nt < 4; ++nt) {
      float iv = invArr[nt * 16 + lq];
#pragma unroll
      for (int r = 0; r < 4; ++r) val[nt][r] *= iv;
    }
    __syncthreads();
  }
#pragma unroll
  for (int nt = 0; nt < 4; ++nt)
#pragma unroll
    for (int r = 0; r < 4; ++r)
      ftile[nt * 16 + lq][wv * 16 + lg * 4 + r] = val[nt][r];
  __syncthreads();
  size_t rowb = (size_t)(b * 8 + h) * N + n0;
  for (int r2 = 0; r2 < 16; ++r2) {
    int n = r2 * 4 + wv;
    float v = ftile[n][lane];
    size_t idx = (rowb + n) * 64 + lane;
    if (PATH == 1 && isV) {
      fv[idx] = v;
    } else {
      fq[idx] = v;
      unsigned short hb = f2h_bits(v);
      sh[idx] = hb;
      sl[idx] = f2h_bits((v - h_bits2f(hb)) * 2048.f);
      if (PATH == 0) b16[idx] = hb;  // f16 copy for attention
    }
  }
}

// ---------------- centroid prep (initial only): csq, -2c split f16 -----------
__global__ void centprep_k(const float* __restrict__ cent, float* __restrict__ csq,
                           unsigned short* __restrict__ cb2h, unsigned short* __restrict__ cb2l) {
  int j = blockIdx.x, lane = threadIdx.x;  // blockDim = 64
  float c = cent[j * 64 + lane];
  float s = c * c;
  for (int off = 32; off; off >>= 1) s += __shfl_xor(s, off);
  if (lane == 0) csq[j] = s;
  float m2 = -2.f * c;
  unsigned short h = f2h_bits(m2);
  cb2h[j * 64 + lane] = h;
  cb2l[j * 64 + lane] = f2h_bits((m2 - h_bits2f(h)) * 2048.f);
}

// ---------------- MFMA nearest-centroid assign (f16 split, LDS-staged) -------
// Deferred-compare pipeline (R18). DUO=0 used for both passes now: 64 pts/
// block doubles resident blocks (4/CU) for wave-level overlap.
template <int DUO>
__global__ __launch_bounds__(256) void assign_mfma_k(
    const unsigned short* __restrict__ xh, const unsigned short* __restrict__ xl,
    const unsigned short* __restrict__ cb2h, const unsigned short* __restrict__ cb2l,
    const float* __restrict__ csq, int* __restrict__ aout) {
  __shared__ __align__(16) unsigned short clds[4][2][1024];  // [buf][hi/lo][16x64]
  int t = threadIdx.x, lane = t & 63, wv = t >> 6;
  int lq = lane & 15, lg = lane >> 4;
  int p0 = blockIdx.x * (DUO ? 128 : 64) + wv * (DUO ? 32 : 16);
  const unsigned short* xbA = xh + (size_t)(p0 + lq) * 64;
  const unsigned short* xlA = xl + (size_t)(p0 + lq) * 64;
  hfx8 ba0 = *(const hfx8*)(xbA + lg * 8);
  hfx8 ba1 = *(const hfx8*)(xbA + 32 + lg * 8);
  hfx8 la0 = *(const hfx8*)(xlA + lg * 8);
  hfx8 la1 = *(const hfx8*)(xlA + 32 + lg * 8);
  hfx8 bb0, bb1, lb0, lb1;
  if (DUO) {
    const unsigned short* xbB = xh + (size_t)(p0 + 16 + lq) * 64;
    const unsigned short* xlB = xl + (size_t)(p0 + 16 + lq) * 64;
    bb0 = *(const hfx8*)(xbB + lg * 8);
    bb1 = *(const hfx8*)(xbB + 32 + lg * 8);
    lb0 = *(const hfx8*)(xlB + lg * 8);
    lb1 = *(const hfx8*)(xlB + 32 + lg * 8);
  }

  int part = t >> 7;
  int abyte = (t & 127) * 16;
  int wbyte = abyte ^ (((abyte >> 7) & 7) << 4);
  const unsigned short* gsrc = (part ? cb2l : cb2h) + (abyte >> 1);
  int rowoff = lq * 128;
  int x0 = (lg * 16) ^ ((lq & 7) << 4);
  int x1 = (64 + lg * 16) ^ ((lq & 7) << 4);

  float bestA = 3.4e38f, bestB = 3.4e38f;
  int jA = 0, jB = 0;

  fx4 pchi0A, pclo0A, pchi1A, pclo1A;
  fx4 pchi0B, pclo0B, pchi1B, pclo1B;

  {
    uint4 r0 = *(const uint4*)(gsrc);
    uint4 r1 = *(const uint4*)(gsrc + 1024);
    *(uint4*)((char*)&clds[0][part][0] + wbyte) = r0;
    *(uint4*)((char*)&clds[1][part][0] + wbyte) = r1;
  }

#define COMPARE_PREV(SBASE)                                                    \
  {                                                                            \
    _Pragma("unroll")                                                          \
    for (int u = 0; u < 2; ++u) {                                              \
      int st_ = (SBASE) + u;                                                   \
      fx4 chi_ = u ? pchi1A : pchi0A;                                          \
      fx4 clo_ = u ? pclo1A : pclo0A;                                          \
      _Pragma("unroll")                                                        \
      for (int r_ = 0; r_ < 4; ++r_) {                                         \
        int j_ = st_ * 16 + lg * 4 + r_;                                       \
        float d2_ = chi_[r_] + clo_[r_] * (1.f / 2048.f);                      \
        if (d2_ < bestA) { bestA = d2_; jA = j_; }                             \
      }                                                                        \
      if (DUO) {                                                               \
        fx4 chiB_ = u ? pchi1B : pchi0B;                                       \
        fx4 cloB_ = u ? pclo1B : pclo0B;                                       \
        _Pragma("unroll")                                                      \
        for (int r_ = 0; r_ < 4; ++r_) {                                       \
          int j_ = st_ * 16 + lg * 4 + r_;                                     \
          float d2_ = chiB_[r_] + cloB_[r_] * (1.f / 2048.f);                  \
          if (d2_ < bestB) { bestB = d2_; jB = j_; }                           \
        }                                                                      \
      }                                                                        \
    }                                                                          \
  }

  for (int s = 0; s < 64; s += 2) {
    __syncthreads();
    uint4 rn0, rn1;
    if (s < 62) {
      rn0 = *(const uint4*)(gsrc + (size_t)(s + 2) * 1024);
      rn1 = *(const uint4*)(gsrc + (size_t)(s + 3) * 1024);
    }
    __builtin_amdgcn_sched_barrier(0);
    fx4 cchi0A, cclo0A, cchi1A, cclo1A;
    fx4 cchi0B, cclo0B, cchi1B, cclo1B;
#pragma unroll
    for (int u = 0; u < 2; ++u) {
      int st = s + u;
      const char* ph = (const char*)&clds[st & 3][0][0];
      const char* pl = (const char*)&clds[st & 3][1][0];
      hfx8 ah0 = *(const hfx8*)(ph + rowoff + x0);
      hfx8 ah1 = *(const hfx8*)(ph + rowoff + x1);
      hfx8 al0 = *(const hfx8*)(pl + rowoff + x0);
      hfx8 al1 = *(const hfx8*)(pl + rowoff + x1);
      fx4 cq = *(const fx4*)(csq + st * 16 + lg * 4);
      {
        fx4 chi = cq;
        chi = __builtin_amdgcn_mfma_f32_16x16x32_f16(ah0, ba0, chi, 0, 0, 0);
        chi = __builtin_amdgcn_mfma_f32_16x16x32_f16(ah1, ba1, chi, 0, 0, 0);
        fx4 clo = (fx4){0.f, 0.f, 0.f, 0.f};
        clo = __builtin_amdgcn_mfma_f32_16x16x32_f16(ah0, la0, clo, 0, 0, 0);
        clo = __builtin_amdgcn_mfma_f32_16x16x32_f16(ah1, la1, clo, 0, 0, 0);
        clo = __builtin_amdgcn_mfma_f32_16x16x32_f16(al0, ba0, clo, 0, 0, 0);
        clo = __builtin_amdgcn_mfma_f32_16x16x32_f16(al1, ba1, clo, 0, 0, 0);
        if (u == 0) { cchi0A = chi; cclo0A = clo; } else { cchi1A = chi; cclo1A = clo; }
      }
      if (DUO) {
        fx4 chi = cq;
        chi = __builtin_amdgcn_mfma_f32_16x16x32_f16(ah0, bb0, chi, 0, 0, 0);
        chi = __builtin_amdgcn_mfma_f32_16x16x32_f16(ah1, bb1, chi, 0, 0, 0);
        fx4 clo = (fx4){0.f, 0.f, 0.f, 0.f};
        clo = __builtin_amdgcn_mfma_f32_16x16x32_f16(ah0, lb0, clo, 0, 0, 0);
        clo = __builtin_amdgcn_mfma_f32_16x16x32_f16(ah1, lb1, clo, 0, 0, 0);
        clo = __builtin_amdgcn_mfma_f32_16x16x32_f16(al0, bb0, clo, 0, 0, 0);
        clo = __builtin_amdgcn_mfma_f32_16x16x32_f16(al1, bb1, clo, 0, 0, 0);
        if (u == 0) { cchi0B = chi; cclo0B = clo; } else { cchi1B = chi; cclo1B = clo; }
      }
    }
    if (s > 0) COMPARE_PREV(s - 2);
    pchi0A = cchi0A; pclo0A = cclo0A; pchi1A = cchi1A; pclo1A = cclo1A;
    if (DUO) { pchi0B = cchi0B; pclo0B = cclo0B; pchi1B = cchi1B; pclo1B = cclo1B; }
    __builtin_amdgcn_sched_barrier(0);
    if (s < 62) {
      *(uint4*)((char*)&clds[(s + 2) & 3][part][0] + wbyte) = rn0;
      *(uint4*)((char*)&clds[(s + 3) & 3][part][0] + wbyte) = rn1;
    }
  }
  COMPARE_PREV(62);
#undef COMPARE_PREV

  {
    float o = __shfl_xor(bestA, 16);
    int oj = __shfl_xor(jA, 16);
    if (o < bestA || (o == bestA && oj < jA)) { bestA = o; jA = oj; }
    o = __shfl_xor(bestA, 32);
    oj = __shfl_xor(jA, 32);
    if (o < bestA || (o == bestA && oj < jA)) { bestA = o; jA = oj; }
  }
  if (DUO) {
    float o = __shfl_xor(bestB, 16);
    int oj = __shfl_xor(jB, 16);
    if (o < bestB || (o == bestB && oj < jB)) { bestB = o; jB = oj; }
    o = __shfl_xor(bestB, 32);
    oj = __shfl_xor(jB, 32);
    if (o < bestB || (o == bestB && oj < jB)) { bestB = o; jB = oj; }
  }
  if (lg == 0) {
    aout[p0 + lq] = jA;
    if (DUO) aout[p0 + 16 + lq] = jB;
  }
}

// ---------------- exact f32 L1 distance to assigned centroid -----------------
__global__ void dist_k(const float* __restrict__ x, const float* __restrict__ cent,
                       const int* __restrict__ asg, float* __restrict__ dout) {
  int t = threadIdx.x, lane = t & 63, wv = t >> 6;
  int p = blockIdx.x * 4 + wv;
  int a = asg[p];
  float v = fabsf(cent[(size_t)a * 64 + lane] - x[(size_t)p * 64 + lane]);
  for (int off = 32; off; off >>= 1) v += __shfl_xor(v, off);
  if (lane == 0) dout[p] = v;
}

// ---------------- segment sum via atomics (wave=point: coalesced) ------------
__global__ void segsum_k(const float* __restrict__ x, const int* __restrict__ asg,
                         float* __restrict__ sums, float* __restrict__ cnt) {
  int t = threadIdx.x, lane = t & 63, wv = t >> 6;
  int p = blockIdx.x * 4 + wv;
  int a = asg[p];
  float v = x[(size_t)p * 64 + lane];
  atomicAdd(&sums[a * 64 + lane], v);
  if (lane == 0) atomicAdd(&cnt[a], 1.0f);
}

// ---------------- centroid update + prep + zero (fused) ----------------------
__global__ __launch_bounds__(256) void centup_prep_k(
    float* __restrict__ cent, float* __restrict__ sums, float* __restrict__ cnt,
    float* __restrict__ csq, unsigned short* __restrict__ cb2h,
    unsigned short* __restrict__ cb2l) {
  int i = blockIdx.x * 256 + threadIdx.x;  // 65536 total; rows never span blocks
  int j = i >> 6, lane = threadIdx.x & 63;
  float c = cnt[j];
  float oldc = cent[i];
  float newc = (c > 0.f) ? sums[i] / fmaxf(c, 1.f) : oldc;
  cent[i] = newc;
  float s = newc * newc;
  for (int off = 32; off; off >>= 1) s += __shfl_xor(s, off);
  if (lane == 0) csq[j] = s;
  float m2 = -2.f * newc;
  unsigned short h = f2h_bits(m2);
  cb2h[i] = h;
  cb2l[i] = f2h_bits((m2 - h_bits2f(h)) * 2048.f);
  sums[i] = 0.f;
  if (lane == 0) cnt[j] = 0.f;
}

// ---------------- per-bh top-1024 by descending dist (stable ties) -----------
__global__ __launch_bounds__(1024) void topk_k(const float* __restrict__ dist,
                                               int* __restrict__ sel) {
  __shared__ unsigned long long keys[2048];
  int bh = blockIdx.x, t = threadIdx.x;
  for (int i = t; i < 2048; i += 1024) {
    float d = dist[bh * 2048 + i];
    unsigned int db = __float_as_uint(d);  // d >= 0 -> monotonic
    keys[i] = ((unsigned long long)db << 32) | (unsigned int)(2047 - i);
  }
  __syncthreads();
  for (int k = 2; k <= 2048; k <<= 1) {
    for (int j = k >> 1; j > 0; j >>= 1) {
      for (int i = t; i < 2048; i += 1024) {
        int ixj = i ^ j;
        if (ixj > i) {
          unsigned long long a = keys[i], b = keys[ixj];
          bool up = ((i & k) == 0);
          bool sw = up ? (a < b) : (a > b);  // descending overall
          if (sw) { keys[i] = b; keys[ixj] = a; }
        }
      }
      __syncthreads();
    }
  }
  if (t < 1024) sel[bh * 1024 + t] = 2047 - (int)(keys[t] & 0xffffffffu);
}

// ---------------- gather selected rows -> kh (f16 row-major), vT (f16 d-major)
__global__ void gatherb_k(const float* __restrict__ kbuf, const float* __restrict__ vbuf,
                          const int* __restrict__ sel, unsigned short* __restrict__ kh,
                          unsigned short* __restrict__ vT) {
  __shared__ unsigned short tile[64][66];
  int t = threadIdx.x, lane = t & 63, wv = t >> 6;
  int bh = blockIdx.y, i0 = blockIdx.x * 64;
  for (int r = 0; r < 16; ++r) {
    int i = r * 4 + wv;
    int src = sel[bh * 1024 + i0 + i];
    float kvv = kbuf[((size_t)bh * 2048 + src) * 64 + lane];
    kh[((size_t)bh * 1024 + i0 + i) * 64 + lane] = f2h_bits(kvv);
    float vv = vbuf[((size_t)bh * 2048 + src) * 64 + lane];
    tile[i][lane] = f2h_bits(vv);
  }
  __syncthreads();
  for (int r = 0; r < 16; ++r) {
    int d = r * 4 + wv;
    vT[((size_t)bh * 64 + d) * 1024 + i0 + lane] = tile[lane][d];
  }
}

// ---------------- MFMA flash attention (f16, K LDS-staged, V direct from L2) -
// V fragments read straight from global (L2-hot per-XCD after block remap);
// loads issued right after the barrier so latency hides under QK + softmax.
// Values identical to the previous LDS path (bit-exact).
__global__ __launch_bounds__(256) void attn_mfma_k(
    const unsigned short* __restrict__ qh, const unsigned short* __restrict__ kh,
    const unsigned short* __restrict__ vT,
    unsigned short* __restrict__ oh, unsigned short* __restrict__ ol) {
  __shared__ __align__(16) unsigned short klds[2][4096];  // [buf][64x64] K tile
  __shared__ __align__(16) unsigned short plds[4][16][72];
  int t = threadIdx.x, lane = t & 63, wv = t >> 6;
  int lq = lane & 15, lg = lane >> 4;
  int id = blockIdx.x;
  int bh = (id & 7) * 2 + ((id >> 3) & 1);
  int q0 = (id >> 4) * 64 + wv * 16;
  const unsigned short* qbase = qh + ((size_t)bh * 4096 + q0 + lq) * 64;
  hfx8 qf0 = *(const hfx8*)(qbase + lg * 8);
  hfx8 qf1 = *(const hfx8*)(qbase + 32 + lg * 8);
  fx4 acc[4];
  for (int nt = 0; nt < 4; ++nt) acc[nt] = (fx4){0.f, 0.f, 0.f, 0.f};
  float lsum = 0.f;
  const unsigned short* kbase = kh + (size_t)bh * 1024 * 64;
  const unsigned short* vbase = vT + (size_t)bh * 64 * 1024;

  // K staging: thread stages 32B per tile
  int srow = t >> 2;
  int scolb = (t & 3) * 32;
  const char* gK = (const char*)kbase + (size_t)srow * 128 + scolb;   // + s*8192
  int sw_w = (srow & 7) << 4;
  int wb0 = srow * 128 + (scolb ^ sw_w);
  int wb1 = srow * 128 + ((scolb + 16) ^ sw_w);

  {
    uint4 k0 = *(const uint4*)(gK);
    uint4 k1 = *(const uint4*)(gK + 16);
    *(uint4*)((char*)&klds[0][0] + wb0) = k0;
    *(uint4*)((char*)&klds[0][0] + wb1) = k1;
  }

  int swr = (lq & 7) << 4;
  int rc0 = (lg * 16) ^ swr;
  int rc1 = (64 + lg * 16) ^ swr;

  for (int s = 0; s < 16; ++s) {
    int cur = s & 1;
    int kt0 = s * 64;
    __syncthreads();
    // issue V fragment loads for THIS tile (L2-hot; consumed after softmax)
    hfx8 vb0[4], vb1[4];
#pragma unroll
    for (int nt = 0; nt < 4; ++nt) {
      const unsigned short* vr = vbase + (size_t)(nt * 16 + lq) * 1024 + kt0 + lg * 8;
      vb0[nt] = *(const hfx8*)(vr);
      vb1[nt] = *(const hfx8*)(vr + 32);
    }
    // prefetch next K tile
    uint4 nk0, nk1;
    if (s < 15) {
      const char* gKn = gK + (size_t)(s + 1) * 8192;
      nk0 = *(const uint4*)(gKn);
      nk1 = *(const uint4*)(gKn + 16);
    }
    __builtin_amdgcn_sched_barrier(0);
    const char* Kb = (const char*)&klds[cur][0];
    fx4 sS[4];
#pragma unroll
    for (int mt = 0; mt < 4; ++mt) {
      int rowb = (mt * 16 + lq) * 128;
      hfx8 a0 = *(const hfx8*)(Kb + rowb + rc0);
      hfx8 a1 = *(const hfx8*)(Kb + rowb + rc1);
      fx4 c = (fx4){0.f, 0.f, 0.f, 0.f};
      c = __builtin_amdgcn_mfma_f32_16x16x32_f16(a0, qf0, c, 0, 0, 0);
      c = __builtin_amdgcn_mfma_f32_16x16x32_f16(a1, qf1, c, 0, 0, 0);
      sS[mt] = c;
    }
#pragma unroll
    for (int mt = 0; mt < 4; ++mt) {
      float p0 = __expf(sS[mt].x), p1 = __expf(sS[mt].y);
      float p2 = __expf(sS[mt].z), p3 = __expf(sS[mt].w);
      lsum += (p0 + p1) + (p2 + p3);
      fpx2 c01 = __builtin_amdgcn_cvt_pkrtz(p0, p1);
      fpx2 c23 = __builtin_amdgcn_cvt_pkrtz(p2, p3);
      unsigned u01, u23;
      __builtin_memcpy(&u01, &c01, 4);
      __builtin_memcpy(&u23, &c23, 4);
      uint2 pk = {u01, u23};
      *(uint2*)&plds[wv][lq][mt * 16 + lg * 4] = pk;
    }
    hfx8 pa0 = *(const hfx8*)&plds[wv][lq][lg * 8];
    hfx8 pa1 = *(const hfx8*)&plds[wv][lq][32 + lg * 8];
#pragma unroll
    for (int nt = 0; nt < 4; ++nt) {
      acc[nt] = __builtin_amdgcn_mfma_f32_16x16x32_f16(pa0, vb0[nt], acc[nt], 0, 0, 0);
      acc[nt] = __builtin_amdgcn_mfma_f32_16x16x32_f16(pa1, vb1[nt], acc[nt], 0, 0, 0);
    }
    __builtin_amdgcn_sched_barrier(0);
    if (s < 15) {
      char* dK = (char*)&klds[cur ^ 1][0];
      *(uint4*)(dK + wb0) = nk0;
      *(uint4*)(dK + wb1) = nk1;
    }
  }
  lsum += __shfl_xor(lsum, 16);
  lsum += __shfl_xor(lsum, 32);
  int bi = bh >> 3, hd = bh & 7;
  for (int r = 0; r < 4; ++r) {
    float inv = 1.f / __shfl(lsum, lg * 4 + r);
    size_t rowb = ((size_t)bi * 4096 + q0 + lg * 4 + r) * 512 + hd * 64;
    for (int nt = 0; nt < 4; ++nt) {
      float val = acc[nt][r] * inv;
      unsigned short hb = f2h_bits(val);
      oh[rowb + nt * 16 + lq] = hb;
      ol[rowb + nt * 16 + lq] = f2h_bits((val - h_bits2f(hb)) * 2048.f);
    }
  }
}

// ---------------- final LN + gamma*ln + residual (wave-split channels) -------
__global__ __launch_bounds__(256) void final_k(
    const float* __restrict__ y, const float* __restrict__ g,
    const float* __restrict__ bta, const float* __restrict__ gamma,
    const float* __restrict__ qs, float* __restrict__ out) {
  __shared__ float p1[4][64], p2[4][64];
  __shared__ float mArr[64], invArr[64];
  int t = threadIdx.x, lane = t & 63, wv = t >> 6;
  int n0 = blockIdx.x * 64, bi = blockIdx.y;
  const float* yb = y + (size_t)bi * CDIM * NQ + n0 + lane;
  float s = 0.f, s2 = 0.f;
  for (int cl = 0; cl < 64; ++cl) {
    float v = yb[(size_t)(wv * 64 + cl) * NQ];
    s += v;
    s2 += v * v;
  }
  p1[wv][lane] = s;
  p2[wv][lane] = s2;
  __syncthreads();
  if (t < 64) {
    float ts = p1[0][t] + p1[1][t] + p1[2][t] + p1[3][t];
    float ts2 = p2[0][t] + p2[1][t] + p2[2][t] + p2[3][t];
    float m = ts / CDIM;
    float var = ts2 / CDIM - m * m;
    mArr[t] = m;
    invArr[t] = 1.f / (sqrtf(fmaxf(var, 0.f)) + 1e-6f);
  }
  __syncthreads();
  float gm = gamma[0];
  float m = mArr[lane], inv = invArr[lane];
  const float* qb = qs + (size_t)bi * CDIM * NQ + n0 + lane;
  float* ob = out + (size_t)bi * CDIM * NQ + n0 + lane;
  for (int cl = 0; cl < 64; ++cl) {
    int c = wv * 64 + cl;
    float v = yb[(size_t)c * NQ];
    float ln = g[c] * (v - m) * inv + bta[c];
    ob[(size_t)c * NQ] = gm * ln + qb[(size_t)c * NQ];
  }
}

extern "C" void kernel_launch(void* const* d_in, const int* in_sizes, int n_in,
                              void* d_out, int out_size, void* d_ws, size_t ws_size,
                              hipStream_t stream) {
  const float* qsrc = (const float*)d_in[0];
  const float* ctx = (const float*)d_in[1];
  const float* w_q = (const float*)d_in[2];
  const float* w_kv = (const float*)d_in[3];
  const float* w_out = (const float*)d_in[4];
  const float* cn_g = (const float*)d_in[5];
  const float* cn_b = (const float*)d_in[6];
  const float* qn_g = (const float*)d_in[7];
  const float* qn_b = (const float*)d_in[8];
  const float* on_g = (const float*)d_in[9];
  const float* on_b = (const float*)d_in[10];
  const float* gamma = (const float*)d_in[11];

  // scratch layout (floats); total 22,267,904 floats = 89.1 MB
  if (ws_size < (size_t)22267904 * 4) return;
  float* ws = (float*)d_ws;
  float* r_ctx = ws;                      // 1,048,576 f: ctx split-f16; later kh/vT
  float* r_kv = r_ctx + 1048576;          // 4,194,304 f: kbh/kbl f16; later attnt split
  float* r_qs = r_kv + 4194304;           // 2,097,152 f: qs split-f16; later cb2h/l, ybuf
  float* r_q3 = r_qs + 2097152;           // 4,194,304 f: qbh/qbl f16
  float* qbuf = r_q3 + 4194304;           // 4,194,304 f
  float* kbuf = qbuf + 4194304;           // 2,097,152 f
  float* vbuf = kbuf + 2097152;           // 2,097,152 f
  float* cent = vbuf + 2097152;           // 65,536 f
  float* csq = cent + 65536;              // 1,024 f
  float* sums = csq + 1024;               // 65,536 f
  float* cnt = sums + 65536;              // 1,024 f
  int* asg = (int*)(cnt + 1024);          // 65,536 i
  float* dist = (float*)(asg + 65536);    // 32,768 f
  int* sel = (int*)(dist + 32768);        // 16,384 i
  float* kgreg = (float*)(sel + 16384);   // 2,097,152 f (qh f16)

  unsigned short* ctxth = (unsigned short*)r_ctx;   // [b][2048][256] f16 hi
  unsigned short* ctxtl = ctxth + (size_t)BB * NK * CDIM;  // lo
  unsigned short* qsth = (unsigned short*)r_qs;     // [b][4096][256] f16 hi
  unsigned short* qstl = qsth + (size_t)BB * NQ * CDIM;    // lo
  unsigned short* qh = (unsigned short*)kgreg;      // 4M f16
  unsigned short* kh = (unsigned short*)r_ctx;      // 1M f16 (ctx split dead)
  unsigned short* vT = kh + 1048576;                // 1M f16
  unsigned short* qbh = (unsigned short*)r_q3;      // 4M f16 (q split hi)
  unsigned short* qbl = qbh + (size_t)NPQ * 64;     // 4M f16 (lo)
  unsigned short* kbh = (unsigned short*)r_kv;      // 2M f16 (k split hi)
  unsigned short* kbl = kbh + (size_t)NPK * 64;     // 2M f16 (lo)
  unsigned short* cb2h = (unsigned short*)r_qs;     // 64K f16 (-2c hi)
  unsigned short* cb2l = cb2h + 65536;              // 64K f16 (lo)
  unsigned short* attnth = (unsigned short*)r_kv;   // [b][4096][512] f16 hi (kb split dead)
  unsigned short* attntl = attnth + (size_t)BB * NQ * 512;  // lo
  float* ybuf = r_qs;                     // [b][256][4096] f32 (cb2 dead)

  // 1. channel LayerNorms -> transposed split-f16
  chan_ln_tsplit_k<<<dim3(NK / 64, BB), 256, 0, stream>>>(ctx, cn_g, cn_b, ctxth, ctxtl, CDIM, NK);
  chan_ln_tsplit_k<<<dim3(NQ / 64, BB), 256, 0, stream>>>(qsrc, qn_g, qn_b, qsth, qstl, CDIM, NQ);
  // 2. fused MFMA projections + fold + L2-norm + format emit (LDS-pipelined)
  gemmfold_k<1><<<dim3(NK / 64, 16, BB), 256, 0, stream>>>(
      w_kv, ctxth, ctxtl, kbuf, kbh, kbl, nullptr, vbuf, CDIM, NK);
  gemmfold_k<0><<<dim3(NQ / 64, 8, BB), 256, 0, stream>>>(
      w_q, qsth, qstl, qbuf, qbh, qbl, qh, nullptr, CDIM, NQ);
  // 3. k-means: initial prep + one memset; centup_prep fuses update/prep/zero
  hipMemcpyAsync(cent, qbuf, 65536 * sizeof(float), hipMemcpyDeviceToDevice, stream);
  centprep_k<<<1024, 64, 0, stream>>>(cent, csq, cb2h, cb2l);
  hipMemsetAsync(sums, 0, (65536 + 1024) * sizeof(float), stream);
  for (int it = 0; it < 4; ++it) {
    assign_mfma_k<0><<<NPQ / 64, 256, 0, stream>>>(qbh, qbl, cb2h, cb2l, csq, asg);
    segsum_k<<<NPQ / 4, 256, 0, stream>>>(qbuf, asg, sums, cnt);
    centup_prep_k<<<65536 / 256, 256, 0, stream>>>(cent, sums, cnt, csq, cb2h, cb2l);
  }
  // 4. score keys: argmin (MFMA) -> exact f32 L1 dist -> per-head top-1024
  assign_mfma_k<0><<<NPK / 64, 256, 0, stream>>>(kbh, kbl, cb2h, cb2l, csq, asg);
  dist_k<<<NPK / 4, 256, 0, stream>>>(kbuf, cent, asg, dist);
  topk_k<<<BH, 1024, 0, stream>>>(dist, sel);
  // 5. gather (kh row-major f16, vT transposed f16)
  gatherb_k<<<dim3(TOPK / 64, BH), 256, 0, stream>>>(kbuf, vbuf, sel, kh, vT);
  // 6. MFMA attention (f16, XCD-mapped, V direct) -> split-f16 [b][n][512]
  attn_mfma_k<<<1024, 256, 0, stream>>>(qh, kh, vT, attnth, attntl);
  // 7. output projection (MFMA, LDS-staged)
  gemm_mfma_k<<<dim3(NQ / 64, 256 / 64, BB), 256, 0, stream>>>(w_out, attnth, attntl, ybuf, 256, 512, NQ);
  // 8. final LN + residual
  final_k<<<dim3(NQ / 64, BB), 256, 0, stream>>>(ybuf, on_g, on_b, gamma, qsrc, (float*)d_out);
}

// Round 20
// 482.524 us; speedup vs baseline: 1.0884x; 1.0884x over previous
//
#include <hip/hip_runtime.h>
#include <math.h>

#define BB 2
#define CDIM 256
#define NQ 4096   // 16*16*16
#define NK 2048   // 8*16*16
#define BH 16
#define TOPK 1024
#define NPQ (BH*NQ)   // 65536
#define NPK (BH*NK)   // 32768

typedef __attribute__((ext_vector_type(8))) short bfx8;
typedef __attribute__((ext_vector_type(8))) _Float16 hfx8;
typedef __attribute__((ext_vector_type(2))) __fp16 fpx2;
typedef __attribute__((ext_vector_type(4))) float fx4;
typedef __attribute__((ext_vector_type(4))) unsigned short us4;

__device__ inline unsigned short f2bf(float x) {
  unsigned u = __float_as_uint(x);
  return (unsigned short)((u + 0x7fffu + ((u >> 16) & 1u)) >> 16);
}
__device__ inline unsigned short f2h_bits(float x) {
  _Float16 h = (_Float16)x;
  unsigned short u;
  __builtin_memcpy(&u, &h, 2);
  return u;
}
__device__ inline float h_bits2f(unsigned short u) {
  _Float16 h;
  __builtin_memcpy(&h, &u, 2);
  return (float)h;
}

// ------- channel LayerNorm -> transposed split-f16 [b][n][C] (hi, lo*2048) ---
__global__ __launch_bounds__(256) void chan_ln_tsplit_k(
    const float* __restrict__ x, const float* __restrict__ g,
    const float* __restrict__ bta, unsigned short* __restrict__ yh,
    unsigned short* __restrict__ yl, int C, int N) {
  __shared__ float tile[4][64][65];
  __shared__ float p1[4][64], p2[4][64];
  __shared__ float mArr[64], invArr[64];
  int t = threadIdx.x, lane = t & 63, wv = t >> 6;
  int n0 = blockIdx.x * 64, bi = blockIdx.y;
  const float* xb = x + (size_t)bi * C * N + n0 + lane;
  float s = 0.f, s2 = 0.f;
  for (int cl = 0; cl < 64; ++cl) {
    float v = xb[(size_t)(wv * 64 + cl) * N];
    tile[wv][cl][lane] = v;
    s += v;
    s2 += v * v;
  }
  p1[wv][lane] = s;
  p2[wv][lane] = s2;
  __syncthreads();
  if (t < 64) {
    float ts = p1[0][t] + p1[1][t] + p1[2][t] + p1[3][t];
    float ts2 = p2[0][t] + p2[1][t] + p2[2][t] + p2[3][t];
    float m = ts / C;
    float var = ts2 / C - m * m;
    mArr[t] = m;
    invArr[t] = 1.f / (sqrtf(fmaxf(var, 0.f)) + 1e-6f);
  }
  __syncthreads();
  int c = wv * 64 + lane;  // lane = channel in phase 2
  float gc = g[c], bc = bta[c];
  unsigned short* ohb = yh + ((size_t)bi * N + n0) * C + c;
  unsigned short* olb = yl + ((size_t)bi * N + n0) * C + c;
  for (int pl = 0; pl < 64; ++pl) {
    float v = tile[wv][lane][pl];
    float ln = gc * (v - mArr[pl]) * invArr[pl] + bc;
    unsigned short hb = f2h_bits(ln);
    ohb[(size_t)pl * C] = hb;
    olb[(size_t)pl * C] = f2h_bits((ln - h_bits2f(hb)) * 2048.f);
  }
}

// ------- MFMA GEMM (w_out), LDS-staged X pipeline: Y[b][o][n] ----------------
__global__ __launch_bounds__(256) void gemm_mfma_k(
    const float* __restrict__ W, const unsigned short* __restrict__ Xh,
    const unsigned short* __restrict__ Xl, float* __restrict__ Y,
    int O, int C, int N) {
  __shared__ __align__(16) unsigned short xlds[2][64][64];  // [buf][row][hi32|lo32]
  int t = threadIdx.x, lane = t & 63, wv = t >> 6;
  int lq = lane & 15, lg = lane >> 4;
  int n0 = blockIdx.x * 64, o0 = blockIdx.y * 64 + wv * 16;
  int b = blockIdx.z;
  const unsigned short* xbh = Xh + ((size_t)b * N + n0) * C;
  const unsigned short* xbl = Xl + ((size_t)b * N + n0) * C;
  const float* wr = W + (size_t)(o0 + lq) * C;

  int a = t * 16;
  int srow = a >> 6;
  int schunk = (a >> 4) & 3;
  const unsigned short* gsh = xbh + (size_t)srow * C + schunk * 8;
  const unsigned short* gsl = xbl + (size_t)srow * C + schunk * 8;
  int swz = (srow & 7) << 4;
  int wbh = srow * 128 + ((schunk * 16) ^ swz);
  int wbl = srow * 128 + ((64 + schunk * 16) ^ swz);
  int rswz = (lq & 7) << 4;
  int xh0 = (lg * 16) ^ rswz;
  int xl0 = (64 + lg * 16) ^ rswz;

  fx4 ahi[4], alo[4];
  for (int nt = 0; nt < 4; ++nt) {
    ahi[nt] = (fx4){0.f, 0.f, 0.f, 0.f};
    alo[nt] = (fx4){0.f, 0.f, 0.f, 0.f};
  }

  {
    uint4 h0 = *(const uint4*)(gsh);
    uint4 l0 = *(const uint4*)(gsl);
    *(uint4*)((char*)&xlds[0][0][0] + wbh) = h0;
    *(uint4*)((char*)&xlds[0][0][0] + wbl) = l0;
  }
  float4 w0c = *(const float4*)(wr + lg * 8);
  float4 w1c = *(const float4*)(wr + lg * 8 + 4);

  int nsteps = C / 32;
  for (int s = 0; s < nsteps; ++s) {
    int cur = s & 1;
    __syncthreads();
    uint4 nh, nl;
    float4 nw0, nw1;
    if (s < nsteps - 1) {
      nh = *(const uint4*)(gsh + (s + 1) * 32);
      nl = *(const uint4*)(gsl + (s + 1) * 32);
      nw0 = *(const float4*)(wr + (s + 1) * 32 + lg * 8);
      nw1 = *(const float4*)(wr + (s + 1) * 32 + lg * 8 + 4);
    }
    __builtin_amdgcn_sched_barrier(0);
    float wv8[8] = {w0c.x, w0c.y, w0c.z, w0c.w, w1c.x, w1c.y, w1c.z, w1c.w};
    hfx8 ah, al;
#pragma unroll
    for (int i = 0; i < 8; ++i) {
      _Float16 hh = (_Float16)wv8[i];
      ah[i] = hh;
      al[i] = (_Float16)((wv8[i] - (float)hh) * 2048.f);
    }
    const char* Xb = (const char*)&xlds[cur][0][0];
#pragma unroll
    for (int nt = 0; nt < 4; ++nt) {
      int rb = (nt * 16 + lq) * 128;
      hfx8 bh = *(const hfx8*)(Xb + rb + xh0);
      hfx8 bl = *(const hfx8*)(Xb + rb + xl0);
      ahi[nt] = __builtin_amdgcn_mfma_f32_16x16x32_f16(ah, bh, ahi[nt], 0, 0, 0);
      alo[nt] = __builtin_amdgcn_mfma_f32_16x16x32_f16(al, bh, alo[nt], 0, 0, 0);
      alo[nt] = __builtin_amdgcn_mfma_f32_16x16x32_f16(ah, bl, alo[nt], 0, 0, 0);
    }
    __builtin_amdgcn_sched_barrier(0);
    if (s < nsteps - 1) {
      *(uint4*)((char*)&xlds[cur ^ 1][0][0] + wbh) = nh;
      *(uint4*)((char*)&xlds[cur ^ 1][0][0] + wbl) = nl;
      w0c = nw0;
      w1c = nw1;
    }
  }
  float* yb = Y + ((size_t)b * O + o0) * N + n0;
#pragma unroll
  for (int nt = 0; nt < 4; ++nt)
#pragma unroll
    for (int r = 0; r < 4; ++r)
      yb[(size_t)(lg * 4 + r) * N + nt * 16 + lq] = ahi[nt][r] + alo[nt][r] * (1.f / 2048.f);
}

// ------- fused GEMM + head-fold + L2-norm + multi-format emit ---------------
template <int PATH>
__global__ __launch_bounds__(256) void gemmfold_k(
    const float* __restrict__ W, const unsigned short* __restrict__ Xh,
    const unsigned short* __restrict__ Xl, float* __restrict__ fq,
    unsigned short* __restrict__ sh, unsigned short* __restrict__ sl,
    unsigned short* __restrict__ b16, float* __restrict__ fv,
    int C, int N) {
  __shared__ __align__(16) unsigned short xlds[2][64][64];  // [buf][row][hi32|lo32]
  __shared__ float ftile[64][65];
  __shared__ float part[4][64];
  __shared__ float invArr[64];
  int t = threadIdx.x, lane = t & 63, wv = t >> 6;
  int lq = lane & 15, lg = lane >> 4;
  int n0 = blockIdx.x * 64, o0 = blockIdx.y * 64 + wv * 16;
  int b = blockIdx.z;
  bool isV = (PATH == 1) && (blockIdx.y >= 8);
  int h = (PATH == 1) ? (blockIdx.y & 7) : blockIdx.y;
  const unsigned short* xbh = Xh + ((size_t)b * N + n0) * C;
  const unsigned short* xbl = Xl + ((size_t)b * N + n0) * C;
  const float* wr = W + (size_t)(o0 + lq) * C;

  int a = t * 16;
  int srow = a >> 6;
  int schunk = (a >> 4) & 3;
  const unsigned short* gsh = xbh + (size_t)srow * C + schunk * 8;
  const unsigned short* gsl = xbl + (size_t)srow * C + schunk * 8;
  int swz = (srow & 7) << 4;
  int wbh = srow * 128 + ((schunk * 16) ^ swz);
  int wbl = srow * 128 + ((64 + schunk * 16) ^ swz);
  int rswz = (lq & 7) << 4;
  int xh0 = (lg * 16) ^ rswz;
  int xl0 = (64 + lg * 16) ^ rswz;

  fx4 ahi[4], alo[4];
  for (int nt = 0; nt < 4; ++nt) {
    ahi[nt] = (fx4){0.f, 0.f, 0.f, 0.f};
    alo[nt] = (fx4){0.f, 0.f, 0.f, 0.f};
  }

  {
    uint4 h0 = *(const uint4*)(gsh);
    uint4 l0 = *(const uint4*)(gsl);
    *(uint4*)((char*)&xlds[0][0][0] + wbh) = h0;
    *(uint4*)((char*)&xlds[0][0][0] + wbl) = l0;
  }
  float4 w0c = *(const float4*)(wr + lg * 8);
  float4 w1c = *(const float4*)(wr + lg * 8 + 4);

  for (int s = 0; s < 8; ++s) {
    int cur = s & 1;
    __syncthreads();
    uint4 nh, nl;
    float4 nw0, nw1;
    if (s < 7) {
      nh = *(const uint4*)(gsh + (s + 1) * 32);
      nl = *(const uint4*)(gsl + (s + 1) * 32);
      nw0 = *(const float4*)(wr + (s + 1) * 32 + lg * 8);
      nw1 = *(const float4*)(wr + (s + 1) * 32 + lg * 8 + 4);
    }
    __builtin_amdgcn_sched_barrier(0);
    float wv8[8] = {w0c.x, w0c.y, w0c.z, w0c.w, w1c.x, w1c.y, w1c.z, w1c.w};
    hfx8 ah, al;
#pragma unroll
    for (int i = 0; i < 8; ++i) {
      _Float16 hh = (_Float16)wv8[i];
      ah[i] = hh;
      al[i] = (_Float16)((wv8[i] - (float)hh) * 2048.f);
    }
    const char* Xb = (const char*)&xlds[cur][0][0];
#pragma unroll
    for (int nt = 0; nt < 4; ++nt) {
      int rb = (nt * 16 + lq) * 128;
      hfx8 bh = *(const hfx8*)(Xb + rb + xh0);
      hfx8 bl = *(const hfx8*)(Xb + rb + xl0);
      ahi[nt] = __builtin_amdgcn_mfma_f32_16x16x32_f16(ah, bh, ahi[nt], 0, 0, 0);
      alo[nt] = __builtin_amdgcn_mfma_f32_16x16x32_f16(al, bh, alo[nt], 0, 0, 0);
      alo[nt] = __builtin_amdgcn_mfma_f32_16x16x32_f16(ah, bl, alo[nt], 0, 0, 0);
    }
    __builtin_amdgcn_sched_barrier(0);
    if (s < 7) {
      *(uint4*)((char*)&xlds[cur ^ 1][0][0] + wbh) = nh;
      *(uint4*)((char*)&xlds[cur ^ 1][0][0] + wbl) = nl;
      w0c = nw0;
      w1c = nw1;
    }
  }

  float val[4][4];
#pragma unroll
  for (int nt = 0; nt < 4; ++nt)
#pragma unroll
    for (int r = 0; r < 4; ++r)
      val[nt][r] = ahi[nt][r] + alo[nt][r] * (1.f / 2048.f);
  __syncthreads();
  if (!isV) {
#pragma unroll
    for (int nt = 0; nt < 4; ++nt) {
      float ss = val[nt][0] * val[nt][0] + val[nt][1] * val[nt][1] +
                 val[nt][2] * val[nt][2] + val[nt][3] * val[nt][3];
      ss += __shfl_xor(ss, 16);
      ss += __shfl_xor(ss, 32);
      if (lg == 0) part[wv][nt * 16 + lq] = ss;
    }
    __syncthreads();
    if (t < 64) {
      float tot = part[0][t] + part[1][t] + part[2][t] + part[3][t];
      invArr[t] = 1.f / fmaxf(sqrtf(tot), 1e-12f);
    }
    __syncthreads();
#pragma unroll
    for (int nt = 0; nt < 4; ++nt) {
      float iv = invArr[nt * 16 + lq];
#pragma unroll
      for (int r = 0; r < 4; ++r) val[nt][r] *= iv;
    }
    __syncthreads();
  }
#pragma unroll
  for (int nt = 0; nt < 4; ++nt)
#pragma unroll
    for (int r = 0; r < 4; ++r)
      ftile[nt * 16 + lq][wv * 16 + lg * 4 + r] = val[nt][r];
  __syncthreads();
  size_t rowb = (size_t)(b * 8 + h) * N + n0;
  for (int r2 = 0; r2 < 16; ++r2) {
    int n = r2 * 4 + wv;
    float v = ftile[n][lane];
    size_t idx = (rowb + n) * 64 + lane;
    if (PATH == 1 && isV) {
      fv[idx] = v;
    } else {
      fq[idx] = v;
      unsigned short hb = f2h_bits(v);
      sh[idx] = hb;
      sl[idx] = f2h_bits((v - h_bits2f(hb)) * 2048.f);
      if (PATH == 0) b16[idx] = hb;  // f16 copy for attention
    }
  }
}

// ---------------- centroid prep (initial only): csq, -2c split f16 -----------
__global__ void centprep_k(const float* __restrict__ cent, float* __restrict__ csq,
                           unsigned short* __restrict__ cb2h, unsigned short* __restrict__ cb2l) {
  int j = blockIdx.x, lane = threadIdx.x;  // blockDim = 64
  float c = cent[j * 64 + lane];
  float s = c * c;
  for (int off = 32; off; off >>= 1) s += __shfl_xor(s, off);
  if (lane == 0) csq[j] = s;
  float m2 = -2.f * c;
  unsigned short h = f2h_bits(m2);
  cb2h[j * 64 + lane] = h;
  cb2l[j * 64 + lane] = f2h_bits((m2 - h_bits2f(h)) * 2048.f);
}

// ---------------- MFMA nearest-centroid assign (f16 split, LDS-staged) -------
// Deferred-compare pipeline (R18): iteration i's (chi,clo) compared during
// iteration i+2's MFMA issue. Bit-exact arithmetic and compare order.
template <int DUO>
__global__ __launch_bounds__(256) void assign_mfma_k(
    const unsigned short* __restrict__ xh, const unsigned short* __restrict__ xl,
    const unsigned short* __restrict__ cb2h, const unsigned short* __restrict__ cb2l,
    const float* __restrict__ csq, int* __restrict__ aout) {
  __shared__ __align__(16) unsigned short clds[4][2][1024];  // [buf][hi/lo][16x64]
  int t = threadIdx.x, lane = t & 63, wv = t >> 6;
  int lq = lane & 15, lg = lane >> 4;
  int p0 = blockIdx.x * (DUO ? 128 : 64) + wv * (DUO ? 32 : 16);
  const unsigned short* xbA = xh + (size_t)(p0 + lq) * 64;
  const unsigned short* xlA = xl + (size_t)(p0 + lq) * 64;
  hfx8 ba0 = *(const hfx8*)(xbA + lg * 8);
  hfx8 ba1 = *(const hfx8*)(xbA + 32 + lg * 8);
  hfx8 la0 = *(const hfx8*)(xlA + lg * 8);
  hfx8 la1 = *(const hfx8*)(xlA + 32 + lg * 8);
  hfx8 bb0, bb1, lb0, lb1;
  if (DUO) {
    const unsigned short* xbB = xh + (size_t)(p0 + 16 + lq) * 64;
    const unsigned short* xlB = xl + (size_t)(p0 + 16 + lq) * 64;
    bb0 = *(const hfx8*)(xbB + lg * 8);
    bb1 = *(const hfx8*)(xbB + 32 + lg * 8);
    lb0 = *(const hfx8*)(xlB + lg * 8);
    lb1 = *(const hfx8*)(xlB + 32 + lg * 8);
  }

  int part = t >> 7;
  int abyte = (t & 127) * 16;
  int wbyte = abyte ^ (((abyte >> 7) & 7) << 4);
  const unsigned short* gsrc = (part ? cb2l : cb2h) + (abyte >> 1);
  int rowoff = lq * 128;
  int x0 = (lg * 16) ^ ((lq & 7) << 4);
  int x1 = (64 + lg * 16) ^ ((lq & 7) << 4);

  float bestA = 3.4e38f, bestB = 3.4e38f;
  int jA = 0, jB = 0;

  fx4 pchi0A, pclo0A, pchi1A, pclo1A;
  fx4 pchi0B, pclo0B, pchi1B, pclo1B;

  {
    uint4 r0 = *(const uint4*)(gsrc);
    uint4 r1 = *(const uint4*)(gsrc + 1024);
    *(uint4*)((char*)&clds[0][part][0] + wbyte) = r0;
    *(uint4*)((char*)&clds[1][part][0] + wbyte) = r1;
  }

#define COMPARE_PREV(SBASE)                                                    \
  {                                                                            \
    _Pragma("unroll")                                                          \
    for (int u = 0; u < 2; ++u) {                                              \
      int st_ = (SBASE) + u;                                                   \
      fx4 chi_ = u ? pchi1A : pchi0A;                                          \
      fx4 clo_ = u ? pclo1A : pclo0A;                                          \
      _Pragma("unroll")                                                        \
      for (int r_ = 0; r_ < 4; ++r_) {                                         \
        int j_ = st_ * 16 + lg * 4 + r_;                                       \
        float d2_ = chi_[r_] + clo_[r_] * (1.f / 2048.f);                      \
        if (d2_ < bestA) { bestA = d2_; jA = j_; }                             \
      }                                                                        \
      if (DUO) {                                                               \
        fx4 chiB_ = u ? pchi1B : pchi0B;                                       \
        fx4 cloB_ = u ? pclo1B : pclo0B;                                       \
        _Pragma("unroll")                                                      \
        for (int r_ = 0; r_ < 4; ++r_) {                                       \
          int j_ = st_ * 16 + lg * 4 + r_;                                     \
          float d2_ = chiB_[r_] + cloB_[r_] * (1.f / 2048.f);                  \
          if (d2_ < bestB) { bestB = d2_; jB = j_; }                           \
        }                                                                      \
      }                                                                        \
    }                                                                          \
  }

  for (int s = 0; s < 64; s += 2) {
    __syncthreads();
    uint4 rn0, rn1;
    if (s < 62) {
      rn0 = *(const uint4*)(gsrc + (size_t)(s + 2) * 1024);
      rn1 = *(const uint4*)(gsrc + (size_t)(s + 3) * 1024);
    }
    __builtin_amdgcn_sched_barrier(0);
    fx4 cchi0A, cclo0A, cchi1A, cclo1A;
    fx4 cchi0B, cclo0B, cchi1B, cclo1B;
#pragma unroll
    for (int u = 0; u < 2; ++u) {
      int st = s + u;
      const char* ph = (const char*)&clds[st & 3][0][0];
      const char* pl = (const char*)&clds[st & 3][1][0];
      hfx8 ah0 = *(const hfx8*)(ph + rowoff + x0);
      hfx8 ah1 = *(const hfx8*)(ph + rowoff + x1);
      hfx8 al0 = *(const hfx8*)(pl + rowoff + x0);
      hfx8 al1 = *(const hfx8*)(pl + rowoff + x1);
      fx4 cq = *(const fx4*)(csq + st * 16 + lg * 4);
      {
        fx4 chi = cq;
        chi = __builtin_amdgcn_mfma_f32_16x16x32_f16(ah0, ba0, chi, 0, 0, 0);
        chi = __builtin_amdgcn_mfma_f32_16x16x32_f16(ah1, ba1, chi, 0, 0, 0);
        fx4 clo = (fx4){0.f, 0.f, 0.f, 0.f};
        clo = __builtin_amdgcn_mfma_f32_16x16x32_f16(ah0, la0, clo, 0, 0, 0);
        clo = __builtin_amdgcn_mfma_f32_16x16x32_f16(ah1, la1, clo, 0, 0, 0);
        clo = __builtin_amdgcn_mfma_f32_16x16x32_f16(al0, ba0, clo, 0, 0, 0);
        clo = __builtin_amdgcn_mfma_f32_16x16x32_f16(al1, ba1, clo, 0, 0, 0);
        if (u == 0) { cchi0A = chi; cclo0A = clo; } else { cchi1A = chi; cclo1A = clo; }
      }
      if (DUO) {
        fx4 chi = cq;
        chi = __builtin_amdgcn_mfma_f32_16x16x32_f16(ah0, bb0, chi, 0, 0, 0);
        chi = __builtin_amdgcn_mfma_f32_16x16x32_f16(ah1, bb1, chi, 0, 0, 0);
        fx4 clo = (fx4){0.f, 0.f, 0.f, 0.f};
        clo = __builtin_amdgcn_mfma_f32_16x16x32_f16(ah0, lb0, clo, 0, 0, 0);
        clo = __builtin_amdgcn_mfma_f32_16x16x32_f16(ah1, lb1, clo, 0, 0, 0);
        clo = __builtin_amdgcn_mfma_f32_16x16x32_f16(al0, bb0, clo, 0, 0, 0);
        clo = __builtin_amdgcn_mfma_f32_16x16x32_f16(al1, bb1, clo, 0, 0, 0);
        if (u == 0) { cchi0B = chi; cclo0B = clo; } else { cchi1B = chi; cclo1B = clo; }
      }
    }
    if (s > 0) COMPARE_PREV(s - 2);
    pchi0A = cchi0A; pclo0A = cclo0A; pchi1A = cchi1A; pclo1A = cclo1A;
    if (DUO) { pchi0B = cchi0B; pclo0B = cclo0B; pchi1B = cchi1B; pclo1B = cclo1B; }
    __builtin_amdgcn_sched_barrier(0);
    if (s < 62) {
      *(uint4*)((char*)&clds[(s + 2) & 3][part][0] + wbyte) = rn0;
      *(uint4*)((char*)&clds[(s + 3) & 3][part][0] + wbyte) = rn1;
    }
  }
  COMPARE_PREV(62);
#undef COMPARE_PREV

  {
    float o = __shfl_xor(bestA, 16);
    int oj = __shfl_xor(jA, 16);
    if (o < bestA || (o == bestA && oj < jA)) { bestA = o; jA = oj; }
    o = __shfl_xor(bestA, 32);
    oj = __shfl_xor(jA, 32);
    if (o < bestA || (o == bestA && oj < jA)) { bestA = o; jA = oj; }
  }
  if (DUO) {
    float o = __shfl_xor(bestB, 16);
    int oj = __shfl_xor(jB, 16);
    if (o < bestB || (o == bestB && oj < jB)) { bestB = o; jB = oj; }
    o = __shfl_xor(bestB, 32);
    oj = __shfl_xor(jB, 32);
    if (o < bestB || (o == bestB && oj < jB)) { bestB = o; jB = oj; }
  }
  if (lg == 0) {
    aout[p0 + lq] = jA;
    if (DUO) aout[p0 + 16 + lq] = jB;
  }
}

// ---------------- exact f32 L1 distance to assigned centroid -----------------
__global__ void dist_k(const float* __restrict__ x, const float* __restrict__ cent,
                       const int* __restrict__ asg, float* __restrict__ dout) {
  int t = threadIdx.x, lane = t & 63, wv = t >> 6;
  int p = blockIdx.x * 4 + wv;
  int a = asg[p];
  float v = fabsf(cent[(size_t)a * 64 + lane] - x[(size_t)p * 64 + lane]);
  for (int off = 32; off; off >>= 1) v += __shfl_xor(v, off);
  if (lane == 0) dout[p] = v;
}

// ---------------- segment sum via atomics (wave=point: coalesced) ------------
__global__ void segsum_k(const float* __restrict__ x, const int* __restrict__ asg,
                         float* __restrict__ sums, float* __restrict__ cnt) {
  int t = threadIdx.x, lane = t & 63, wv = t >> 6;
  int p = blockIdx.x * 4 + wv;
  int a = asg[p];
  float v = x[(size_t)p * 64 + lane];
  atomicAdd(&sums[a * 64 + lane], v);
  if (lane == 0) atomicAdd(&cnt[a], 1.0f);
}

// ---------------- centroid update + prep + zero (fused) ----------------------
__global__ __launch_bounds__(256) void centup_prep_k(
    float* __restrict__ cent, float* __restrict__ sums, float* __restrict__ cnt,
    float* __restrict__ csq, unsigned short* __restrict__ cb2h,
    unsigned short* __restrict__ cb2l) {
  int i = blockIdx.x * 256 + threadIdx.x;  // 65536 total; rows never span blocks
  int j = i >> 6, lane = threadIdx.x & 63;
  float c = cnt[j];
  float oldc = cent[i];
  float newc = (c > 0.f) ? sums[i] / fmaxf(c, 1.f) : oldc;
  cent[i] = newc;
  float s = newc * newc;
  for (int off = 32; off; off >>= 1) s += __shfl_xor(s, off);
  if (lane == 0) csq[j] = s;
  float m2 = -2.f * newc;
  unsigned short h = f2h_bits(m2);
  cb2h[i] = h;
  cb2l[i] = f2h_bits((m2 - h_bits2f(h)) * 2048.f);
  sums[i] = 0.f;
  if (lane == 0) cnt[j] = 0.f;
}

// ---------------- per-bh top-1024 by descending dist (stable ties) -----------
__global__ __launch_bounds__(1024) void topk_k(const float* __restrict__ dist,
                                               int* __restrict__ sel) {
  __shared__ unsigned long long keys[2048];
  int bh = blockIdx.x, t = threadIdx.x;
  for (int i = t; i < 2048; i += 1024) {
    float d = dist[bh * 2048 + i];
    unsigned int db = __float_as_uint(d);  // d >= 0 -> monotonic
    keys[i] = ((unsigned long long)db << 32) | (unsigned int)(2047 - i);
  }
  __syncthreads();
  for (int k = 2; k <= 2048; k <<= 1) {
    for (int j = k >> 1; j > 0; j >>= 1) {
      for (int i = t; i < 2048; i += 1024) {
        int ixj = i ^ j;
        if (ixj > i) {
          unsigned long long a = keys[i], b = keys[ixj];
          bool up = ((i & k) == 0);
          bool sw = up ? (a < b) : (a > b);  // descending overall
          if (sw) { keys[i] = b; keys[ixj] = a; }
        }
      }
      __syncthreads();
    }
  }
  if (t < 1024) sel[bh * 1024 + t] = 2047 - (int)(keys[t] & 0xffffffffu);
}

// ---------------- gather selected rows -> kh (f16 row-major), vT (f16 d-major)
__global__ void gatherb_k(const float* __restrict__ kbuf, const float* __restrict__ vbuf,
                          const int* __restrict__ sel, unsigned short* __restrict__ kh,
                          unsigned short* __restrict__ vT) {
  __shared__ unsigned short tile[64][66];
  int t = threadIdx.x, lane = t & 63, wv = t >> 6;
  int bh = blockIdx.y, i0 = blockIdx.x * 64;
  for (int r = 0; r < 16; ++r) {
    int i = r * 4 + wv;
    int src = sel[bh * 1024 + i0 + i];
    float kvv = kbuf[((size_t)bh * 2048 + src) * 64 + lane];
    kh[((size_t)bh * 1024 + i0 + i) * 64 + lane] = f2h_bits(kvv);
    float vv = vbuf[((size_t)bh * 2048 + src) * 64 + lane];
    tile[i][lane] = f2h_bits(vv);
  }
  __syncthreads();
  for (int r = 0; r < 16; ++r) {
    int d = r * 4 + wv;
    vT[((size_t)bh * 64 + d) * 1024 + i0 + lane] = tile[lane][d];
  }
}

// ---------------- MFMA flash attention (f16, K/V LDS-staged, XCD-mapped) -----
__global__ __launch_bounds__(256) void attn_mfma_k(
    const unsigned short* __restrict__ qh, const unsigned short* __restrict__ kh,
    const unsigned short* __restrict__ vT,
    unsigned short* __restrict__ oh, unsigned short* __restrict__ ol) {
  __shared__ __align__(16) unsigned short kvlds[2][2][4096];  // [buf][K/V][64x64]
  __shared__ __align__(16) unsigned short plds[4][16][72];
  int t = threadIdx.x, lane = t & 63, wv = t >> 6;
  int lq = lane & 15, lg = lane >> 4;
  int id = blockIdx.x;
  int bh = (id & 7) * 2 + ((id >> 3) & 1);
  int q0 = (id >> 4) * 64 + wv * 16;
  const unsigned short* qbase = qh + ((size_t)bh * 4096 + q0 + lq) * 64;
  hfx8 qf0 = *(const hfx8*)(qbase + lg * 8);
  hfx8 qf1 = *(const hfx8*)(qbase + 32 + lg * 8);
  fx4 acc[4];
  for (int nt = 0; nt < 4; ++nt) acc[nt] = (fx4){0.f, 0.f, 0.f, 0.f};
  float lsum = 0.f;
  const unsigned short* kbase = kh + (size_t)bh * 1024 * 64;
  const unsigned short* vbase = vT + (size_t)bh * 64 * 1024;

  int srow = t >> 2;
  int scolb = (t & 3) * 32;
  const char* gK = (const char*)kbase + (size_t)srow * 128 + scolb;   // + s*8192
  const char* gV = (const char*)vbase + (size_t)srow * 2048 + scolb;  // + s*128
  int sw_w = (srow & 7) << 4;
  int wb0 = srow * 128 + (scolb ^ sw_w);
  int wb1 = srow * 128 + ((scolb + 16) ^ sw_w);

  {
    uint4 k0 = *(const uint4*)(gK);
    uint4 k1 = *(const uint4*)(gK + 16);
    uint4 v0 = *(const uint4*)(gV);
    uint4 v1 = *(const uint4*)(gV + 16);
    *(uint4*)((char*)&kvlds[0][0][0] + wb0) = k0;
    *(uint4*)((char*)&kvlds[0][0][0] + wb1) = k1;
    *(uint4*)((char*)&kvlds[0][1][0] + wb0) = v0;
    *(uint4*)((char*)&kvlds[0][1][0] + wb1) = v1;
  }

  int swr = (lq & 7) << 4;
  int rc0 = (lg * 16) ^ swr;
  int rc1 = (64 + lg * 16) ^ swr;

  for (int s = 0; s < 16; ++s) {
    int cur = s & 1;
    __syncthreads();
    uint4 nk0, nk1, nv0, nv1;
    if (s < 15) {
      const char* gKn = gK + (size_t)(s + 1) * 8192;
      const char* gVn = gV + (size_t)(s + 1) * 128;
      nk0 = *(const uint4*)(gKn);
      nk1 = *(const uint4*)(gKn + 16);
      nv0 = *(const uint4*)(gVn);
      nv1 = *(const uint4*)(gVn + 16);
    }
    __builtin_amdgcn_sched_barrier(0);
    const char* Kb = (const char*)&kvlds[cur][0][0];
    const char* Vb = (const char*)&kvlds[cur][1][0];
    fx4 sS[4];
#pragma unroll
    for (int mt = 0; mt < 4; ++mt) {
      int rowb = (mt * 16 + lq) * 128;
      hfx8 a0 = *(const hfx8*)(Kb + rowb + rc0);
      hfx8 a1 = *(const hfx8*)(Kb + rowb + rc1);
      fx4 c = (fx4){0.f, 0.f, 0.f, 0.f};
      c = __builtin_amdgcn_mfma_f32_16x16x32_f16(a0, qf0, c, 0, 0, 0);
      c = __builtin_amdgcn_mfma_f32_16x16x32_f16(a1, qf1, c, 0, 0, 0);
      sS[mt] = c;
    }
#pragma unroll
    for (int mt = 0; mt < 4; ++mt) {
      float p0 = __expf(sS[mt].x), p1 = __expf(sS[mt].y);
      float p2 = __expf(sS[mt].z), p3 = __expf(sS[mt].w);
      lsum += (p0 + p1) + (p2 + p3);
      fpx2 c01 = __builtin_amdgcn_cvt_pkrtz(p0, p1);
      fpx2 c23 = __builtin_amdgcn_cvt_pkrtz(p2, p3);
      unsigned u01, u23;
      __builtin_memcpy(&u01, &c01, 4);
      __builtin_memcpy(&u23, &c23, 4);
      uint2 pk = {u01, u23};
      *(uint2*)&plds[wv][lq][mt * 16 + lg * 4] = pk;
    }
    hfx8 pa0 = *(const hfx8*)&plds[wv][lq][lg * 8];
    hfx8 pa1 = *(const hfx8*)&plds[wv][lq][32 + lg * 8];
#pragma unroll
    for (int nt = 0; nt < 4; ++nt) {
      int rowb = (nt * 16 + lq) * 128;
      hfx8 b0 = *(const hfx8*)(Vb + rowb + rc0);
      hfx8 b1 = *(const hfx8*)(Vb + rowb + rc1);
      acc[nt] = __builtin_amdgcn_mfma_f32_16x16x32_f16(pa0, b0, acc[nt], 0, 0, 0);
      acc[nt] = __builtin_amdgcn_mfma_f32_16x16x32_f16(pa1, b1, acc[nt], 0, 0, 0);
    }
    __builtin_amdgcn_sched_barrier(0);
    if (s < 15) {
      char* dK = (char*)&kvlds[cur ^ 1][0][0];
      char* dV = (char*)&kvlds[cur ^ 1][1][0];
      *(uint4*)(dK + wb0) = nk0;
      *(uint4*)(dK + wb1) = nk1;
      *(uint4*)(dV + wb0) = nv0;
      *(uint4*)(dV + wb1) = nv1;
    }
  }
  lsum += __shfl_xor(lsum, 16);
  lsum += __shfl_xor(lsum, 32);
  int bi = bh >> 3, hd = bh & 7;
  for (int r = 0; r < 4; ++r) {
    float inv = 1.f / __shfl(lsum, lg * 4 + r);
    size_t rowb = ((size_t)bi * 4096 + q0 + lg * 4 + r) * 512 + hd * 64;
    for (int nt = 0; nt < 4; ++nt) {
      float val = acc[nt][r] * inv;
      unsigned short hb = f2h_bits(val);
      oh[rowb + nt * 16 + lq] = hb;
      ol[rowb + nt * 16 + lq] = f2h_bits((val - h_bits2f(hb)) * 2048.f);
    }
  }
}

// ---------------- final LN + gamma*ln + residual (wave-split channels) -------
__global__ __launch_bounds__(256) void final_k(
    const float* __restrict__ y, const float* __restrict__ g,
    const float* __restrict__ bta, const float* __restrict__ gamma,
    const float* __restrict__ qs, float* __restrict__ out) {
  __shared__ float p1[4][64], p2[4][64];
  __shared__ float mArr[64], invArr[64];
  int t = threadIdx.x, lane = t & 63, wv = t >> 6;
  int n0 = blockIdx.x * 64, bi = blockIdx.y;
  const float* yb = y + (size_t)bi * CDIM * NQ + n0 + lane;
  float s = 0.f, s2 = 0.f;
  for (int cl = 0; cl < 64; ++cl) {
    float v = yb[(size_t)(wv * 64 + cl) * NQ];
    s += v;
    s2 += v * v;
  }
  p1[wv][lane] = s;
  p2[wv][lane] = s2;
  __syncthreads();
  if (t < 64) {
    float ts = p1[0][t] + p1[1][t] + p1[2][t] + p1[3][t];
    float ts2 = p2[0][t] + p2[1][t] + p2[2][t] + p2[3][t];
    float m = ts / CDIM;
    float var = ts2 / CDIM - m * m;
    mArr[t] = m;
    invArr[t] = 1.f / (sqrtf(fmaxf(var, 0.f)) + 1e-6f);
  }
  __syncthreads();
  float gm = gamma[0];
  float m = mArr[lane], inv = invArr[lane];
  const float* qb = qs + (size_t)bi * CDIM * NQ + n0 + lane;
  float* ob = out + (size_t)bi * CDIM * NQ + n0 + lane;
  for (int cl = 0; cl < 64; ++cl) {
    int c = wv * 64 + cl;
    float v = yb[(size_t)c * NQ];
    float ln = g[c] * (v - m) * inv + bta[c];
    ob[(size_t)c * NQ] = gm * ln + qb[(size_t)c * NQ];
  }
}

extern "C" void kernel_launch(void* const* d_in, const int* in_sizes, int n_in,
                              void* d_out, int out_size, void* d_ws, size_t ws_size,
                              hipStream_t stream) {
  const float* qsrc = (const float*)d_in[0];
  const float* ctx = (const float*)d_in[1];
  const float* w_q = (const float*)d_in[2];
  const float* w_kv = (const float*)d_in[3];
  const float* w_out = (const float*)d_in[4];
  const float* cn_g = (const float*)d_in[5];
  const float* cn_b = (const float*)d_in[6];
  const float* qn_g = (const float*)d_in[7];
  const float* qn_b = (const float*)d_in[8];
  const float* on_g = (const float*)d_in[9];
  const float* on_b = (const float*)d_in[10];
  const float* gamma = (const float*)d_in[11];

  // scratch layout (floats); total 22,267,904 floats = 89.1 MB
  if (ws_size < (size_t)22267904 * 4) return;
  float* ws = (float*)d_ws;
  float* r_ctx = ws;                      // 1,048,576 f: ctx split-f16; later kh/vT
  float* r_kv = r_ctx + 1048576;          // 4,194,304 f: kbh/kbl f16; later attnt split
  float* r_qs = r_kv + 4194304;           // 2,097,152 f: qs split-f16; later cb2h/l, ybuf
  float* r_q3 = r_qs + 2097152;           // 4,194,304 f: qbh/qbl f16
  float* qbuf = r_q3 + 4194304;           // 4,194,304 f
  float* kbuf = qbuf + 4194304;           // 2,097,152 f
  float* vbuf = kbuf + 2097152;           // 2,097,152 f
  float* cent = vbuf + 2097152;           // 65,536 f
  float* csq = cent + 65536;              // 1,024 f
  float* sums = csq + 1024;               // 65,536 f
  float* cnt = sums + 65536;              // 1,024 f
  int* asg = (int*)(cnt + 1024);          // 65,536 i
  float* dist = (float*)(asg + 65536);    // 32,768 f
  int* sel = (int*)(dist + 32768);        // 16,384 i
  float* kgreg = (float*)(sel + 16384);   // 2,097,152 f (qh f16)

  unsigned short* ctxth = (unsigned short*)r_ctx;   // [b][2048][256] f16 hi
  unsigned short* ctxtl = ctxth + (size_t)BB * NK * CDIM;  // lo
  unsigned short* qsth = (unsigned short*)r_qs;     // [b][4096][256] f16 hi
  unsigned short* qstl = qsth + (size_t)BB * NQ * CDIM;    // lo
  unsigned short* qh = (unsigned short*)kgreg;      // 4M f16
  unsigned short* kh = (unsigned short*)r_ctx;      // 1M f16 (ctx split dead)
  unsigned short* vT = kh + 1048576;                // 1M f16
  unsigned short* qbh = (unsigned short*)r_q3;      // 4M f16 (q split hi)
  unsigned short* qbl = qbh + (size_t)NPQ * 64;     // 4M f16 (lo)
  unsigned short* kbh = (unsigned short*)r_kv;      // 2M f16 (k split hi)
  unsigned short* kbl = kbh + (size_t)NPK * 64;     // 2M f16 (lo)
  unsigned short* cb2h = (unsigned short*)r_qs;     // 64K f16 (-2c hi)
  unsigned short* cb2l = cb2h + 65536;              // 64K f16 (lo)
  unsigned short* attnth = (unsigned short*)r_kv;   // [b][4096][512] f16 hi (kb split dead)
  unsigned short* attntl = attnth + (size_t)BB * NQ * 512;  // lo
  float* ybuf = r_qs;                     // [b][256][4096] f32 (cb2 dead)

  // 1. channel LayerNorms -> transposed split-f16
  chan_ln_tsplit_k<<<dim3(NK / 64, BB), 256, 0, stream>>>(ctx, cn_g, cn_b, ctxth, ctxtl, CDIM, NK);
  chan_ln_tsplit_k<<<dim3(NQ / 64, BB), 256, 0, stream>>>(qsrc, qn_g, qn_b, qsth, qstl, CDIM, NQ);
  // 2. fused MFMA projections + fold + L2-norm + format emit (LDS-pipelined)
  gemmfold_k<1><<<dim3(NK / 64, 16, BB), 256, 0, stream>>>(
      w_kv, ctxth, ctxtl, kbuf, kbh, kbl, nullptr, vbuf, CDIM, NK);
  gemmfold_k<0><<<dim3(NQ / 64, 8, BB), 256, 0, stream>>>(
      w_q, qsth, qstl, qbuf, qbh, qbl, qh, nullptr, CDIM, NQ);
  // 3. k-means: initial prep + one memset; centup_prep fuses update/prep/zero
  hipMemcpyAsync(cent, qbuf, 65536 * sizeof(float), hipMemcpyDeviceToDevice, stream);
  centprep_k<<<1024, 64, 0, stream>>>(cent, csq, cb2h, cb2l);
  hipMemsetAsync(sums, 0, (65536 + 1024) * sizeof(float), stream);
  for (int it = 0; it < 4; ++it) {
    assign_mfma_k<1><<<NPQ / 128, 256, 0, stream>>>(qbh, qbl, cb2h, cb2l, csq, asg);
    segsum_k<<<NPQ / 4, 256, 0, stream>>>(qbuf, asg, sums, cnt);
    centup_prep_k<<<65536 / 256, 256, 0, stream>>>(cent, sums, cnt, csq, cb2h, cb2l);
  }
  // 4. score keys: argmin (MFMA) -> exact f32 L1 dist -> per-head top-1024
  assign_mfma_k<0><<<NPK / 64, 256, 0, stream>>>(kbh, kbl, cb2h, cb2l, csq, asg);
  dist_k<<<NPK / 4, 256, 0, stream>>>(kbuf, cent, asg, dist);
  topk_k<<<BH, 1024, 0, stream>>>(dist, sel);
  // 5. gather (kh row-major f16, vT transposed f16)
  gatherb_k<<<dim3(TOPK / 64, BH), 256, 0, stream>>>(kbuf, vbuf, sel, kh, vT);
  // 6. MFMA attention (f16, XCD-mapped) -> split-f16 un-folded [b][n][512]
  attn_mfma_k<<<1024, 256, 0, stream>>>(qh, kh, vT, attnth, attntl);
  // 7. output projection (MFMA, LDS-staged)
  gemm_mfma_k<<<dim3(NQ / 64, 256 / 64, BB), 256, 0, stream>>>(w_out, attnth, attntl, ybuf, 256, 512, NQ);
  // 8. final LN + residual
  final_k<<<dim3(NQ / 64, BB), 256, 0, stream>>>(ybuf, on_g, on_b, gamma, qsrc, (float*)d_out);
}